// Round 16
// baseline (343.382 us; speedup 1.0000x reference)
//
#include <hip/hip_runtime.h>
#include <hip/hip_bf16.h>

typedef __bf16 bf16x8 __attribute__((ext_vector_type(8)));
typedef float  f32x4  __attribute__((ext_vector_type(4)));

// ---------- helpers ----------
static __device__ __forceinline__ unsigned short f2bf(float f) {
  unsigned int u = __float_as_uint(f);
  u += 0x7FFFu + ((u >> 16) & 1u);   // round-to-nearest-even
  return (unsigned short)(u >> 16);
}

static __device__ __forceinline__ void gl_lds16(const void* g, void* l) {
  __builtin_amdgcn_global_load_lds(
      (const __attribute__((address_space(1))) void*)g,
      (__attribute__((address_space(3))) void*)l,
      16, 0, 0);
}

// ---------- cast x: f32 -> bf16 ----------
__global__ __launch_bounds__(256) void cast_f32_bf16(
    const float* __restrict__ in, unsigned short* __restrict__ out, int n) {
  int i = (blockIdx.x * 256 + threadIdx.x) * 4;
  const int stride = gridDim.x * 256 * 4;
  for (; i < n; i += stride) {
    float4 f = *(const float4*)(in + i);
    ushort4 o;
    o.x = f2bf(f.x); o.y = f2bf(f.y); o.z = f2bf(f.z); o.w = f2bf(f.w);
    *(ushort4*)(out + i) = o;
  }
}

// ---------- transpose-cast Wq|Wk|Wv in one launch (z picks the matrix) ----------
__global__ __launch_bounds__(256) void transpose_cast_w3(
    const float* __restrict__ w0, const float* __restrict__ w1,
    const float* __restrict__ w2, unsigned short* __restrict__ wt) {
  __shared__ float tile[16][17];
  const float* w = blockIdx.z == 0 ? w0 : (blockIdx.z == 1 ? w1 : w2);
  unsigned short* o = wt + (size_t)blockIdx.z * 1048576;
  const int tx = threadIdx.x & 15, ty = threadIdx.x >> 4;
  const int bx = blockIdx.x * 16, by = blockIdx.y * 16;
  tile[ty][tx] = w[(size_t)(by + ty) * 1024 + bx + tx];
  __syncthreads();
  o[(size_t)(bx + ty) * 1024 + by + tx] = f2bf(tile[tx][ty]);
}

// ---------- QKV: 128x128-tile, BK=64 single buffer, 512 threads (r15 winner) ----------
// 8 waves/block x 4 LDS-resident blocks = up to 32 waves/CU: occ 74%,
// MfmaUtil 31.7, 144 us measured (vs 164 at 256 threads). Per-wave 64x32.
// Fused-QKV split write: col<1024 -> q; <2048 -> k; else vT[(b*1024+e)*2048+s].
__global__ __launch_bounds__(512, 7) void gemm_qkv(
    const unsigned short* __restrict__ A, int lda,
    const unsigned short* __restrict__ B, int ldb,
    int K, void* __restrict__ Cv) {
  __shared__ __align__(16) unsigned char lds[32768];  // A 16K [kk][row][64B] | B 16K
  const unsigned d2 = blockIdx.x + gridDim.x * blockIdx.y;
  const unsigned ty = d2 % gridDim.y;     // gy%8==0 -> A-panel XCD-local
  const unsigned tx = d2 / gridDim.y;
  const int bm0 = ty * 128;
  const int bn0 = tx * 128;

  const int tid = threadIdx.x;
  const int wid = tid >> 6, lane = tid & 63;
  const int wr = wid >> 2, wc = wid & 3;     // wave grid 2(M) x 4(N)
  const int l15 = lane & 15, kq = lane >> 4;

  const int sr = tid >> 2;
  const int ssub = (tid & 3) * 8;
  const size_t aoff = (size_t)(bm0 + sr) * lda + ssub;
  const size_t boff = (size_t)(bn0 + sr) * ldb + ssub;
  unsigned char* dstA = lds + wid * 1024;
  unsigned char* dstB = lds + 16384 + wid * 1024;

  f32x4 acc[4][2] = {};
  const int nkt = K >> 6;
  for (int kt = 0; kt < nkt; ++kt) {
    const int kc = kt << 6;
    gl_lds16(A + aoff + kc,      dstA);
    gl_lds16(A + aoff + kc + 32, dstA + 8192);
    gl_lds16(B + boff + kc,      dstB);
    gl_lds16(B + boff + kc + 32, dstB + 8192);
    __syncthreads();

#pragma unroll
    for (int kk = 0; kk < 2; ++kk) {
      bf16x8 af[4], bg[2];
#pragma unroll
      for (int mi = 0; mi < 4; ++mi)
        af[mi] = *(const bf16x8*)(lds + kk * 8192 + (wr * 64 + mi * 16 + l15) * 64 + kq * 16);
#pragma unroll
      for (int ni = 0; ni < 2; ++ni)
        bg[ni] = *(const bf16x8*)(lds + 16384 + kk * 8192 + (wc * 32 + ni * 16 + l15) * 64 + kq * 16);
#pragma unroll
      for (int mi = 0; mi < 4; ++mi)
#pragma unroll
        for (int ni = 0; ni < 2; ++ni)
          acc[mi][ni] = __builtin_amdgcn_mfma_f32_16x16x32_bf16(af[mi], bg[ni], acc[mi][ni], 0, 0, 0);
    }
    __syncthreads();
  }

  // epilogue: C/D layout col = lane&15, row = (lane>>4)*4 + reg
#pragma unroll
  for (int mi = 0; mi < 4; ++mi)
#pragma unroll
    for (int ni = 0; ni < 2; ++ni)
#pragma unroll
      for (int r = 0; r < 4; ++r) {
        const int row = bm0 + wr * 64 + mi * 16 + kq * 4 + r;
        const int col = bn0 + wc * 32 + ni * 16 + l15;
        const float v = acc[mi][ni][r];
        unsigned short* q = (unsigned short*)Cv;
        if (col < 1024) {
          q[(size_t)row * 1024 + col] = f2bf(v);
        } else if (col < 2048) {
          q[16777216u + (size_t)row * 1024 + (col - 1024)] = f2bf(v);
        } else {
          const int b = row >> 11, s = row & 2047;
          q[33554432u + ((size_t)(b * 1024 + (col - 2048))) * 2048 + s] = f2bf(v);
        }
      }
}

// ---------- attention GEMMs: 128x128-tile, BK=64, 256 threads (r14 best) ----------
// 512-thr variant regressed attention ~20 us (worse ds_read/MFMA ratio at
// 64x32/wave + conflicts 1.26e7->1.89e7); these shapes have >=2048/1024
// blocks so occupancy is already block-count-rich at 256 threads.
// MODE 4: scores + fused exp + per-block partial row-sums
// MODE 5: PV; inv computed IN-BLOCK from the 16 partials
template <int MODE>
__global__ __launch_bounds__(256, 2) void gemm_att(
    const unsigned short* __restrict__ A, int lda, size_t astride,
    const unsigned short* __restrict__ B, int ldb, size_t bstride,
    int K, void* __restrict__ Cv, int ldc, size_t cstride,
    float* __restrict__ aux) {
  __shared__ __align__(16) unsigned char lds[32768];  // A 16K | B 16K
  __shared__ float smInv[128];
  const unsigned d2 = blockIdx.x + gridDim.x * blockIdx.y;
  const unsigned ty = d2 % gridDim.y;
  const unsigned tx = d2 / gridDim.y;
  const int bn0 = tx * 128;
  const int bm0 = ty * 128;
  A += (size_t)blockIdx.z * astride;
  B += (size_t)blockIdx.z * bstride;

  const int tid = threadIdx.x;
  const int wid = tid >> 6, lane = tid & 63;
  const int wr = wid >> 1, wc = wid & 1;
  const int l15 = lane & 15, kq = lane >> 4;

  if constexpr (MODE == 5) {  // inv[row] for this block's 128 rows
    if (tid < 128) {
      const float* p = aux + (size_t)blockIdx.z * 32768 + bm0 + tid;
      float s = 0.f;
#pragma unroll
      for (int j = 0; j < 16; ++j) s += p[j * 2048];
      smInv[tid] = 1.0f / s;   // visible after iter-0 __syncthreads
    }
  }

  // staging: chunk c = j*256 + tid -> kk = j>>1, row = (j&1)*64 + tid>>2, sub = tid&3
  const int sr = tid >> 2;
  const int ssub = (tid & 3) * 8;
  size_t aoff[4], boff[4];
#pragma unroll
  for (int j = 0; j < 4; ++j) {
    const int r = (j & 1) * 64 + sr;
    const int kko = (j >> 1) * 32;
    aoff[j] = (size_t)(bm0 + r) * lda + kko + ssub;
    boff[j] = (size_t)(bn0 + r) * ldb + kko + ssub;
  }
  unsigned char* dstA = lds + wid * 1024;           // + j*4096
  unsigned char* dstB = lds + 16384 + wid * 1024;   // + j*4096

  f32x4 acc[4][4] = {};
  const int nkt = K >> 6;
  for (int kt = 0; kt < nkt; ++kt) {
    const int kc = kt << 6;
#pragma unroll
    for (int j = 0; j < 4; ++j) {
      gl_lds16(A + aoff[j] + kc, dstA + j * 4096);
      gl_lds16(B + boff[j] + kc, dstB + j * 4096);
    }
    __syncthreads();

#pragma unroll
    for (int kk = 0; kk < 2; ++kk) {
      bf16x8 af[4], bg[4];
#pragma unroll
      for (int mi = 0; mi < 4; ++mi)
        af[mi] = *(const bf16x8*)(lds + kk * 8192 + (wr * 64 + mi * 16 + l15) * 64 + kq * 16);
#pragma unroll
      for (int ni = 0; ni < 4; ++ni)
        bg[ni] = *(const bf16x8*)(lds + 16384 + kk * 8192 + (wc * 64 + ni * 16 + l15) * 64 + kq * 16);
#pragma unroll
      for (int mi = 0; mi < 4; ++mi)
#pragma unroll
        for (int ni = 0; ni < 4; ++ni)
          acc[mi][ni] = __builtin_amdgcn_mfma_f32_16x16x32_bf16(af[mi], bg[ni], acc[mi][ni], 0, 0, 0);
    }
    __syncthreads();
  }

  // epilogue: C/D layout col = lane&15, row = (lane>>4)*4 + reg
  if constexpr (MODE == 4) {
    __shared__ float redsm[128][2];
    unsigned short* pp = (unsigned short*)Cv + (size_t)blockIdx.z * cstride;
    float rs[4][4];
#pragma unroll
    for (int mi = 0; mi < 4; ++mi)
#pragma unroll
      for (int r = 0; r < 4; ++r) rs[mi][r] = 0.f;
#pragma unroll
    for (int mi = 0; mi < 4; ++mi)
#pragma unroll
      for (int ni = 0; ni < 4; ++ni)
#pragma unroll
        for (int r = 0; r < 4; ++r) {
          const float e = exp2f(acc[mi][ni][r] * 0.045084220027780106f);  // exp(acc/32)
          rs[mi][r] += e;
          const int row = bm0 + wr * 64 + mi * 16 + kq * 4 + r;
          const int col = bn0 + wc * 64 + ni * 16 + l15;
          pp[(size_t)row * ldc + col] = f2bf(e);
        }
#pragma unroll
    for (int mi = 0; mi < 4; ++mi)
#pragma unroll
      for (int r = 0; r < 4; ++r) {
        float s = rs[mi][r];
        s += __shfl_xor(s, 1); s += __shfl_xor(s, 2);
        s += __shfl_xor(s, 4); s += __shfl_xor(s, 8);
        rs[mi][r] = s;
      }
    if (l15 == 0) {
#pragma unroll
      for (int mi = 0; mi < 4; ++mi)
#pragma unroll
        for (int r = 0; r < 4; ++r)
          redsm[wr * 64 + mi * 16 + kq * 4 + r][wc] = rs[mi][r];
    }
    __syncthreads();
    if (tid < 128)
      aux[((size_t)blockIdx.z * 16 + tx) * 2048 + bm0 + tid] =
          redsm[tid][0] + redsm[tid][1];
  } else {  // MODE 5
    float* op = (float*)Cv + (size_t)blockIdx.z * cstride;
#pragma unroll
    for (int mi = 0; mi < 4; ++mi)
#pragma unroll
      for (int r = 0; r < 4; ++r) {
        const int row = bm0 + wr * 64 + mi * 16 + kq * 4 + r;
        const float iv = smInv[wr * 64 + mi * 16 + kq * 4 + r];
#pragma unroll
        for (int ni = 0; ni < 4; ++ni) {
          const int col = bn0 + wc * 64 + ni * 16 + l15;
          op[(size_t)row * ldc + col] = acc[mi][ni][r] * iv;
        }
      }
  }
}

// ---------- launch ----------
extern "C" void kernel_launch(void* const* d_in, const int* in_sizes, int n_in,
                              void* d_out, int out_size, void* d_ws, size_t ws_size,
                              hipStream_t stream) {
  const float* x  = (const float*)d_in[0];
  const float* Wq = (const float*)d_in[1];
  const float* Wk = (const float*)d_in[2];
  const float* Wv = (const float*)d_in[3];
  float* out = (float*)d_out;
  char* ws = (char*)d_ws;

  // workspace layout (bytes)
  unsigned short* xb     = (unsigned short*)ws;                  // 33.5 MB (dead after QKV)
  unsigned short* wt_all = (unsigned short*)(ws + 33554432);     // 6 MB: WqT|WkT|WvT [3072][1024]
  unsigned short* qb     = (unsigned short*)(ws + 39845888);     // 33.5 MB
  unsigned short* kb     = qb + 16777216;                        // 33.5 MB
  unsigned short* vt     = kb + 16777216;                        // 33.5 MB (vT: [b*1024+e][s])
  const size_t off_scores = 140509184ull;                        // end of vt

  // per-batch attention scratch: P' bf16 8 MiB + partials 128 KiB
  const size_t per_b = 8388608ull + 131072ull;
  int G; char *pPc, *partc;
  const size_t avail = ws_size > off_scores ? ws_size - off_scores : 0;
  G = (int)(avail / per_b); if (G > 8) G = 8;
  if (G >= 1) {
    pPc   = ws + off_scores;
    partc = pPc + (size_t)G * 8388608ull;
  } else {
    G = 2;  // fallback: reuse xb region (33.5 MB >= 2 x 8.53 MB); xb dead after QKV
    pPc   = ws;
    partc = ws + 2 * 8388608ull;
  }

  cast_f32_bf16<<<2048, 256, 0, stream>>>(x, xb, 16384 * 1024);
  transpose_cast_w3<<<dim3(64, 64, 3), 256, 0, stream>>>(Wq, Wk, Wv, wt_all);

  // fused QKV projection: M=16384, N=3072, K=1024 -- 512-thread blocks (occ 74%)
  gemm_qkv<<<dim3(24, 128), 512, 0, stream>>>(xb, 1024, wt_all, 1024, 1024, qb);

  for (int b0 = 0; b0 < 8; b0 += G) {
    const int g = (8 - b0) < G ? (8 - b0) : G;
    const size_t so = (size_t)b0 * 2097152;  // q/k/v/out batch offset (elems)
    // P' = exp(q.k^T/32) bf16 + partial row sums: M=N=2048, K=1024
    gemm_att<4><<<dim3(16, 16, g), 256, 0, stream>>>(
        qb + so, 1024, 2097152, kb + so, 1024, 2097152, 1024,
        (unsigned short*)pPc, 2048, 4194304, (float*)partc);
    // out = (P'.v) * inv : A=P' [2048][2048] bf16, B^T = vT_b [1024][2048], K=2048
    gemm_att<5><<<dim3(8, 16, g), 256, 0, stream>>>(
        (const unsigned short*)pPc, 2048, 4194304,
        vt + so, 2048, 2097152, 2048,
        out + so, 1024, 2097152, (float*)partc);
  }
}

// Round 17
// 303.856 us; speedup vs baseline: 1.1301x; 1.1301x over previous
//
#include <hip/hip_runtime.h>
#include <hip/hip_bf16.h>

typedef __bf16 bf16x8 __attribute__((ext_vector_type(8)));
typedef float  f32x4  __attribute__((ext_vector_type(4)));

// ---------- helpers ----------
static __device__ __forceinline__ unsigned short f2bf(float f) {
  unsigned int u = __float_as_uint(f);
  u += 0x7FFFu + ((u >> 16) & 1u);   // round-to-nearest-even
  return (unsigned short)(u >> 16);
}

static __device__ __forceinline__ void gl_lds16(const void* g, void* l) {
  __builtin_amdgcn_global_load_lds(
      (const __attribute__((address_space(1))) void*)g,
      (__attribute__((address_space(3))) void*)l,
      16, 0, 0);
}

// ---------- cast x: f32 -> bf16 ----------
__global__ __launch_bounds__(256) void cast_f32_bf16(
    const float* __restrict__ in, unsigned short* __restrict__ out, int n) {
  int i = (blockIdx.x * 256 + threadIdx.x) * 4;
  const int stride = gridDim.x * 256 * 4;
  for (; i < n; i += stride) {
    float4 f = *(const float4*)(in + i);
    ushort4 o;
    o.x = f2bf(f.x); o.y = f2bf(f.y); o.z = f2bf(f.z); o.w = f2bf(f.w);
    *(ushort4*)(out + i) = o;
  }
}

// ---------- transpose-cast Wq|Wk|Wv in one launch (z picks the matrix) ----------
__global__ __launch_bounds__(256) void transpose_cast_w3(
    const float* __restrict__ w0, const float* __restrict__ w1,
    const float* __restrict__ w2, unsigned short* __restrict__ wt) {
  __shared__ float tile[16][17];
  const float* w = blockIdx.z == 0 ? w0 : (blockIdx.z == 1 ? w1 : w2);
  unsigned short* o = wt + (size_t)blockIdx.z * 1048576;
  const int tx = threadIdx.x & 15, ty = threadIdx.x >> 4;
  const int bx = blockIdx.x * 16, by = blockIdx.y * 16;
  tile[ty][tx] = w[(size_t)(by + ty) * 1024 + bx + tx];
  __syncthreads();
  o[(size_t)(bx + ty) * 1024 + by + tx] = f2bf(tile[tx][ty]);
}

// ---------- 256x128-tile bf16 GEMM, BK=64 single buffer, 8 waves (4M x 2N) ----------
// The untested good cell: r15's wave count (8 waves/block) + r7/r14's per-wave
// tile (64x64, acc[4][4]) = 32 MFMA per 16 ds_read per K-tile AND high
// residency. r10's 256^2 failure was acc[8][4]=128 AGPR -> 2 waves/SIMD; here
// acc 64 AGPR + ~60 VGPR fits the 128 boundary -> 4 waves/SIMD, LDS 48K -> 3
// blocks/CU -> ~16 waves/CU. Staging 192 B/MFMA (vs 256 in r14/r15).
// LDS: A 32K [kk 0..1][row 0..255][32e=64B] | B 16K [kk][row 0..127][64B].
// Staging = 16 consecutive rows x 64 B contiguous per wave-load, linear dest;
// fragment ds_read_b128 row-stride 64 B (conflict-floor). 6 gl_lds/thread/iter.
// XCD remap: d2 -> (ty=d2%gy, tx=d2/gy); gy%8==0 -> A-panel sharers same XCD.
// MODE 3: fused-QKV split write (Cv = qb base; kb = +16Mi elems, vt = +32Mi)
// MODE 4: scores + fused exp(acc/32) + per-block partial row-sums
// MODE 5: PV; inv computed IN-BLOCK from the 16 partials
template <int MODE>
__global__ __launch_bounds__(512, 4) void gemm_bt(
    const unsigned short* __restrict__ A, int lda, size_t astride,
    const unsigned short* __restrict__ B, int ldb, size_t bstride,
    int K, void* __restrict__ Cv, int ldc, size_t cstride,
    float* __restrict__ aux) {
  __shared__ __align__(16) unsigned char lds[49152];  // A 32K | B 16K
  __shared__ float smInv[256];
  const unsigned d2 = blockIdx.x + gridDim.x * blockIdx.y;
  const unsigned ty = d2 % gridDim.y;
  const unsigned tx = d2 / gridDim.y;
  const int bm0 = ty * 256;
  const int bn0 = tx * 128;
  A += (size_t)blockIdx.z * astride;
  B += (size_t)blockIdx.z * bstride;

  const int tid = threadIdx.x;
  const int wid = tid >> 6, lane = tid & 63;
  const int wr = wid >> 1, wc = wid & 1;     // wave grid 4(M) x 2(N)
  const int l15 = lane & 15, kq = lane >> 4;

  if constexpr (MODE == 5) {  // inv[row] for this block's 256 rows
    if (tid < 256) {
      const float* p = aux + (size_t)blockIdx.z * 32768 + bm0 + tid;
      float s = 0.f;
#pragma unroll
      for (int j = 0; j < 16; ++j) s += p[j * 2048];
      smInv[tid] = 1.0f / s;   // visible after iter-0 __syncthreads
    }
  }

  // staging: A rows j*128 + (tid>>2) (j=0,1) x kk=0,1; B rows tid>>2 x kk=0,1.
  const int sr = tid >> 2;
  const int ssub = (tid & 3) * 8;
  size_t aoff[2][2], boff[2];
#pragma unroll
  for (int kk = 0; kk < 2; ++kk) {
#pragma unroll
    for (int j = 0; j < 2; ++j)
      aoff[kk][j] = (size_t)(bm0 + j * 128 + sr) * lda + kk * 32 + ssub;
    boff[kk] = (size_t)(bn0 + sr) * ldb + kk * 32 + ssub;
  }
  unsigned char* dstA = lds + wid * 1024;            // + kk*16384 + j*8192
  unsigned char* dstB = lds + 32768 + wid * 1024;    // + kk*8192

  f32x4 acc[4][4] = {};
  const int nkt = K >> 6;
  for (int kt = 0; kt < nkt; ++kt) {
    const int kc = kt << 6;
#pragma unroll
    for (int kk = 0; kk < 2; ++kk) {
#pragma unroll
      for (int j = 0; j < 2; ++j)
        gl_lds16(A + aoff[kk][j] + kc, dstA + kk * 16384 + j * 8192);
      gl_lds16(B + boff[kk] + kc, dstB + kk * 8192);
    }
    __syncthreads();

#pragma unroll
    for (int kk = 0; kk < 2; ++kk) {
      bf16x8 af[4], bg[4];
#pragma unroll
      for (int mi = 0; mi < 4; ++mi)
        af[mi] = *(const bf16x8*)(lds + kk * 16384 + (wr * 64 + mi * 16 + l15) * 64 + kq * 16);
#pragma unroll
      for (int ni = 0; ni < 4; ++ni)
        bg[ni] = *(const bf16x8*)(lds + 32768 + kk * 8192 + (wc * 64 + ni * 16 + l15) * 64 + kq * 16);
#pragma unroll
      for (int mi = 0; mi < 4; ++mi)
#pragma unroll
        for (int ni = 0; ni < 4; ++ni)
          acc[mi][ni] = __builtin_amdgcn_mfma_f32_16x16x32_bf16(af[mi], bg[ni], acc[mi][ni], 0, 0, 0);
    }
    __syncthreads();
  }

  // epilogue: C/D layout col = lane&15, row = (lane>>4)*4 + reg  [verified m89/m91]
  if constexpr (MODE == 3) {
#pragma unroll
    for (int mi = 0; mi < 4; ++mi)
#pragma unroll
      for (int ni = 0; ni < 4; ++ni)
#pragma unroll
        for (int r = 0; r < 4; ++r) {
          const int row = bm0 + wr * 64 + mi * 16 + kq * 4 + r;
          const int col = bn0 + wc * 64 + ni * 16 + l15;
          const float v = acc[mi][ni][r];
          unsigned short* q = (unsigned short*)Cv;
          if (col < 1024) {
            q[(size_t)row * 1024 + col] = f2bf(v);
          } else if (col < 2048) {
            q[16777216u + (size_t)row * 1024 + (col - 1024)] = f2bf(v);
          } else {
            const int b = row >> 11, s = row & 2047;
            q[33554432u + ((size_t)(b * 1024 + (col - 2048))) * 2048 + s] = f2bf(v);
          }
        }
  } else if constexpr (MODE == 4) {
    __shared__ float redsm[256][2];
    unsigned short* pp = (unsigned short*)Cv + (size_t)blockIdx.z * cstride;
    float rs[4][4];
#pragma unroll
    for (int mi = 0; mi < 4; ++mi)
#pragma unroll
      for (int r = 0; r < 4; ++r) rs[mi][r] = 0.f;
#pragma unroll
    for (int mi = 0; mi < 4; ++mi)
#pragma unroll
      for (int ni = 0; ni < 4; ++ni)
#pragma unroll
        for (int r = 0; r < 4; ++r) {
          const float e = exp2f(acc[mi][ni][r] * 0.045084220027780106f);  // exp(acc/32)
          rs[mi][r] += e;
          const int row = bm0 + wr * 64 + mi * 16 + kq * 4 + r;
          const int col = bn0 + wc * 64 + ni * 16 + l15;
          pp[(size_t)row * ldc + col] = f2bf(e);
        }
#pragma unroll
    for (int mi = 0; mi < 4; ++mi)
#pragma unroll
      for (int r = 0; r < 4; ++r) {
        float s = rs[mi][r];
        s += __shfl_xor(s, 1); s += __shfl_xor(s, 2);
        s += __shfl_xor(s, 4); s += __shfl_xor(s, 8);
        rs[mi][r] = s;
      }
    if (l15 == 0) {
#pragma unroll
      for (int mi = 0; mi < 4; ++mi)
#pragma unroll
        for (int r = 0; r < 4; ++r)
          redsm[wr * 64 + mi * 16 + kq * 4 + r][wc] = rs[mi][r];
    }
    __syncthreads();
    if (tid < 256)
      aux[((size_t)blockIdx.z * 16 + tx) * 2048 + bm0 + tid] =
          redsm[tid][0] + redsm[tid][1];
  } else {  // MODE 5
    float* op = (float*)Cv + (size_t)blockIdx.z * cstride;
#pragma unroll
    for (int mi = 0; mi < 4; ++mi)
#pragma unroll
      for (int r = 0; r < 4; ++r) {
        const int row = bm0 + wr * 64 + mi * 16 + kq * 4 + r;
        const float iv = smInv[wr * 64 + mi * 16 + kq * 4 + r];
#pragma unroll
        for (int ni = 0; ni < 4; ++ni) {
          const int col = bn0 + wc * 64 + ni * 16 + l15;
          op[(size_t)row * ldc + col] = acc[mi][ni][r] * iv;
        }
      }
  }
}

// ---------- launch ----------
extern "C" void kernel_launch(void* const* d_in, const int* in_sizes, int n_in,
                              void* d_out, int out_size, void* d_ws, size_t ws_size,
                              hipStream_t stream) {
  const float* x  = (const float*)d_in[0];
  const float* Wq = (const float*)d_in[1];
  const float* Wk = (const float*)d_in[2];
  const float* Wv = (const float*)d_in[3];
  float* out = (float*)d_out;
  char* ws = (char*)d_ws;

  // workspace layout (bytes)
  unsigned short* xb     = (unsigned short*)ws;                  // 33.5 MB (dead after QKV)
  unsigned short* wt_all = (unsigned short*)(ws + 33554432);     // 6 MB: WqT|WkT|WvT [3072][1024]
  unsigned short* qb     = (unsigned short*)(ws + 39845888);     // 33.5 MB
  unsigned short* kb     = qb + 16777216;                        // 33.5 MB
  unsigned short* vt     = kb + 16777216;                        // 33.5 MB (vT: [b*1024+e][s])
  const size_t off_scores = 140509184ull;                        // end of vt

  // per-batch attention scratch: P' bf16 8 MiB + partials 128 KiB
  const size_t per_b = 8388608ull + 131072ull;
  int G; char *pPc, *partc;
  const size_t avail = ws_size > off_scores ? ws_size - off_scores : 0;
  G = (int)(avail / per_b); if (G > 8) G = 8;
  if (G >= 1) {
    pPc   = ws + off_scores;
    partc = pPc + (size_t)G * 8388608ull;
  } else {
    G = 2;  // fallback: reuse xb region (33.5 MB >= 2 x 8.53 MB); xb dead after QKV
    pPc   = ws;
    partc = ws + 2 * 8388608ull;
  }

  cast_f32_bf16<<<2048, 256, 0, stream>>>(x, xb, 16384 * 1024);
  transpose_cast_w3<<<dim3(64, 64, 3), 256, 0, stream>>>(Wq, Wk, Wv, wt_all);

  // fused QKV projection: M=16384, N=3072, K=1024 -- 256x128 tiles, grid 24 x 64
  gemm_bt<3><<<dim3(24, 64), 512, 0, stream>>>(xb, 1024, 0, wt_all, 1024, 0,
                                               1024, qb, 0, 0, nullptr);

  for (int b0 = 0; b0 < 8; b0 += G) {
    const int g = (8 - b0) < G ? (8 - b0) : G;
    const size_t so = (size_t)b0 * 2097152;  // q/k/v/out batch offset (elems)
    // P' = exp(q.k^T/32) bf16 + partial row sums: M=N=2048, K=1024 -- grid 16 x 8
    gemm_bt<4><<<dim3(16, 8, g), 512, 0, stream>>>(
        qb + so, 1024, 2097152, kb + so, 1024, 2097152, 1024,
        (unsigned short*)pPc, 2048, 4194304, (float*)partc);
    // out = (P'.v) * inv : A=P' [2048][2048] bf16, B^T = vT_b [1024][2048], K=2048 -- grid 8 x 8
    gemm_bt<5><<<dim3(8, 8, g), 512, 0, stream>>>(
        (const unsigned short*)pPc, 2048, 4194304,
        vt + so, 2048, 2097152, 2048,
        out + so, 1024, 2097152, (float*)partc);
  }
}